// Round 5
// baseline (260.562 us; speedup 1.0000x reference)
//
#include <hip/hip_runtime.h>
#include <cstdint>

#define E_DIM 1024
#define NROWS 32768
#define LDT 1028                // padded LDS tile row stride (floats)
#define INV_SQRT8 0.35355339059327373f

typedef __bf16 bf16x8 __attribute__((ext_vector_type(8)));
typedef float f32x4 __attribute__((ext_vector_type(4)));
typedef const __attribute__((address_space(1))) void* gas_t;
typedef __attribute__((address_space(3))) void* las_t;

// ---------------- setup: fold W'=W@w, emit MFMA-fragment-swizzled bf16 tables ----------------
// WpHS/WpLS: [32 step][64 lane][8 j]  (hi/lo split of [Wq@w | Wk@w], B-frag order)
// WvS:       [4 ct][32 step][64 lane][8 j] of Wv (B-frag order)
__global__ __launch_bounds__(256) void favor_setup(
    const float* __restrict__ w,     // [64][8]
    const float* __restrict__ Wq,    // [1024][64]
    const float* __restrict__ bq,    // [64]
    const float* __restrict__ Wk,    // [1024][64]
    const float* __restrict__ bk,    // [64]
    const float* __restrict__ Wv,    // [1024][64]
    float* __restrict__ bqw,         // [8]
    float* __restrict__ bkw,         // [8]
    __bf16* __restrict__ WpHS,
    __bf16* __restrict__ WpLS,
    __bf16* __restrict__ WvS)
{
    const int g = blockIdx.x * 256 + threadIdx.x;  // 0..16383
    {
        const int k = g >> 4;
        const int c = g & 15;
        const float* Wsrc = (c < 8) ? Wq : Wk;
        const int cc = c & 7;
        float s = 0.f;
        #pragma unroll 8
        for (int d = 0; d < 64; ++d)
            s += Wsrc[k * 64 + d] * w[d * 8 + cc];
        const __bf16 h = (__bf16)s;
        const int step = k >> 5, quad = (k >> 3) & 3, j = k & 7;
        const int lane = quad * 16 + c;
        const int idx = (step * 64 + lane) * 8 + j;
        WpHS[idx] = h;
        WpLS[idx] = (__bf16)(s - (float)h);
    }
    #pragma unroll
    for (int t = 0; t < 4; ++t) {
        const int idx = g * 4 + t;        // [0, 65536)
        const int n = idx >> 10;          // 0..63
        const int k = idx & 1023;
        const int ct = n >> 4, l15 = n & 15;
        const int step = k >> 5, quad = (k >> 3) & 3, j = k & 7;
        const int lane = quad * 16 + l15;
        WvS[(((ct * 32 + step) * 64) + lane) * 8 + j] = (__bf16)Wv[k * 64 + n];
    }
    if (g < 16) {
        const int col = g & 7;
        const float* bb = (g < 8) ? bq : bk;
        float s1 = 0.f;
        #pragma unroll 8
        for (int d = 0; d < 64; ++d)
            s1 += bb[d] * w[d * 8 + col];
        if (g < 8) bqw[col] = s1; else bkw[col] = s1;
    }
}

// ---------------- main ----------------
// grid 2048 x 256. Block = 16 rows, full K=1024, single 64KB staged tile
// (row stride LDT=1028 floats -> balanced LDS banks). Wave wv = K-quarter.
// One load barrier per block; barrier-free MFMA loop; cross-block overlap
// (2 blocks/CU, 8 sequential per CU) hides the single drain.
__global__ __launch_bounds__(256, 2) void favor_main(
    const float* __restrict__ x,      // [NROWS][1024]
    const __bf16* __restrict__ WvS,   // [4][32][64][8]
    const __bf16* __restrict__ WpHS,  // [32][64][8]
    const __bf16* __restrict__ WpLS,  // [32][64][8]
    const float* __restrict__ bqw,    // [8]
    const float* __restrict__ bkw,    // [8]
    const float* __restrict__ bv,     // [64]
    float* __restrict__ pq_out,       // [NROWS][8]
    float* __restrict__ Sbkt)         // [128][4][1024]
{
    __shared__ __align__(16) float smem[16 * LDT];   // 65792 B
    // post-loop overlays (each use separated by barriers):
    float* bufW = smem;           // [3][64][20] combine payload
    float* vb   = smem + 4096;    // [16][68]
    float* kp   = smem + 5248;    // [16][16]
    float* sred = smem + 5632;    // [3][64][20]

    const int tid  = threadIdx.x;
    const int wg   = blockIdx.x;                                // 0..2047
    const int lane = tid & 63;
    const int wv   = __builtin_amdgcn_readfirstlane(tid >> 6);  // 0..3
    const int l15  = lane & 15;
    const int quad = lane >> 4;

    // ---- staging: wave wv loads rows wv*4..+4, 4 chunks of 1KB each, lane-contiguous ----
    {
        const int sr = wv * 4;
        const float* xs = x + ((long)wg * 16 + sr) * E_DIM + lane * 4;
        #pragma unroll
        for (int r = 0; r < 4; ++r)
            #pragma unroll
            for (int c = 0; c < 4; ++c)
                __builtin_amdgcn_global_load_lds(
                    (gas_t)(xs + r * E_DIM + c * 256),
                    (las_t)(smem + (sr + r) * LDT + c * 256), 16, 0, 0);
    }

    f32x4 zero = {0.f, 0.f, 0.f, 0.f};
    f32x4 accv[4];
    #pragma unroll
    for (int ct = 0; ct < 4; ++ct) accv[ct] = zero;
    f32x4 accp = zero;

    __syncthreads();   // single load drain for the whole block

    // ---- barrier-free K-loop: wave wv covers cols [wv*256, wv*256+256) ----
    const int cb = wv * 256;
    #pragma unroll
    for (int ks = 0; ks < 8; ++ks) {
        const float* ap = smem + l15 * LDT + cb + ks * 32 + quad * 8;
        const float4 a0 = *(const float4*)ap;
        const float4 a1 = *(const float4*)(ap + 4);
        bf16x8 ah, al;
        {
            const float f[8] = {a0.x, a0.y, a0.z, a0.w, a1.x, a1.y, a1.z, a1.w};
            #pragma unroll
            for (int i = 0; i < 8; ++i) {
                const __bf16 h = (__bf16)f[i];
                ah[i] = h; al[i] = (__bf16)(f[i] - (float)h);
            }
        }
        const int gs = wv * 8 + ks;
        const __bf16* bp = WvS + (long)gs * 512 + lane * 8;
        #pragma unroll
        for (int ct = 0; ct < 4; ++ct) {
            const bf16x8 b = *(const bf16x8*)(bp + ct * 16384);
            accv[ct] = __builtin_amdgcn_mfma_f32_16x16x32_bf16(ah, b, accv[ct], 0, 0, 0);
        }
        {
            const bf16x8 bh = *(const bf16x8*)(WpHS + (long)gs * 512 + lane * 8);
            const bf16x8 bl = *(const bf16x8*)(WpLS + (long)gs * 512 + lane * 8);
            accp = __builtin_amdgcn_mfma_f32_16x16x32_bf16(ah, bh, accp, 0, 0, 0);
            accp = __builtin_amdgcn_mfma_f32_16x16x32_bf16(al, bh, accp, 0, 0, 0);
            accp = __builtin_amdgcn_mfma_f32_16x16x32_bf16(ah, bl, accp, 0, 0, 0);
        }
    }
    __syncthreads();   // tile dead; overlays become usable

    // ---- combine K-quarters: waves 1..3 dump, wave 0 sums ----
    if (wv != 0) {
        float* dst = bufW + ((wv - 1) * 64 + lane) * 20;
        #pragma unroll
        for (int ct = 0; ct < 4; ++ct)
            *(f32x4*)(dst + ct * 4) = accv[ct];
        *(f32x4*)(dst + 16) = accp;
    }
    __syncthreads();
    if (wv == 0) {
        #pragma unroll
        for (int j = 0; j < 3; ++j) {
            const float* src = bufW + (j * 64 + lane) * 20;
            #pragma unroll
            for (int ct = 0; ct < 4; ++ct)
                accv[ct] += *(const f32x4*)(src + ct * 4);
            accp += *(const f32x4*)(src + 16);
        }
        // ---- p epilogue: accp[r] = P[row = quad*4 + r][c = l15] ----
        if (l15 < 8) {
            const float bq_ = bqw[l15];
            #pragma unroll
            for (int r = 0; r < 4; ++r) {
                const long gr = (long)wg * 16 + quad * 4 + r;
                pq_out[gr * 8 + l15] = accp[r] + bq_;
            }
        } else {
            const float bk_ = bkw[l15 - 8];
            #pragma unroll
            for (int r = 0; r < 4; ++r) {
                const int lr = quad * 4 + r;
                const float pk_ = accp[r] + bk_;
                kp[lr * 16 + (l15 - 8)] = __cosf(pk_) * INV_SQRT8;
                kp[lr * 16 + l15]       = __sinf(pk_) * INV_SQRT8;
            }
        }
        // ---- v epilogue: C/D layout col=lane&15, row=quad*4+reg ----
        #pragma unroll
        for (int ct = 0; ct < 4; ++ct) {
            const float bv_ = bv[ct * 16 + l15];
            #pragma unroll
            for (int r = 0; r < 4; ++r)
                vb[(quad * 4 + r) * 68 + ct * 16 + l15] = accv[ct][r] + bv_;
        }
    }
    __syncthreads();

    // ---- S partial: S[m][d] += sum_r kp[r][m]*vb[r][d] over 16 rows ----
    {
        const int d4 = l15;          // d block of 4
        const int mg = quad;         // m block of 4
        const int rq = wv;           // row quarter (4 rows)
        float sa[16];
        #pragma unroll
        for (int i = 0; i < 16; ++i) sa[i] = 0.f;
        #pragma unroll
        for (int rr = 0; rr < 4; ++rr) {
            const int r = rq * 4 + rr;
            const float4 vv  = *(const float4*)(vb + r * 68 + d4 * 4);
            const float4 kk4 = *(const float4*)(kp + r * 16 + mg * 4);
            const float km[4] = {kk4.x, kk4.y, kk4.z, kk4.w};
            const float vm[4] = {vv.x, vv.y, vv.z, vv.w};
            #pragma unroll
            for (int mi = 0; mi < 4; ++mi)
                #pragma unroll
                for (int di = 0; di < 4; ++di)
                    sa[mi * 4 + di] += km[mi] * vm[di];
        }
        if (rq > 0) {
            float* dst = sred + ((rq - 1) * 64 + lane) * 20;
            #pragma unroll
            for (int i = 0; i < 4; ++i)
                *(float4*)(dst + i * 4) = make_float4(sa[i*4], sa[i*4+1], sa[i*4+2], sa[i*4+3]);
        }
        __syncthreads();
        if (rq == 0) {
            #pragma unroll
            for (int j = 0; j < 3; ++j) {
                const float* src = sred + (j * 64 + lane) * 20;
                #pragma unroll
                for (int i = 0; i < 16; ++i) sa[i] += src[i];
            }
            // bucket = wg & 127, batch = wg >> 9 -> 4 writers per address
            float* Sb = Sbkt + ((long)(wg & 127) * 4 + (wg >> 9)) * 1024;
            #pragma unroll
            for (int mi = 0; mi < 4; ++mi)
                #pragma unroll
                for (int di = 0; di < 4; ++di)
                    atomicAdd(&Sb[(mg * 4 + mi) * 64 + d4 * 4 + di], sa[mi * 4 + di]);
        }
    }
}

// ---------------- reduce buckets -> S ----------------
__global__ __launch_bounds__(256) void favor_reduce(
    const float* __restrict__ Sbkt,   // [128][4][1024]
    float* __restrict__ S)            // [4][1024]
{
    const int g = blockIdx.x * 256 + threadIdx.x;   // [0,4096)
    const int b = g >> 10;
    const int col = g & 1023;
    float s = 0.f;
    #pragma unroll 8
    for (int j = 0; j < 128; ++j)
        s += Sbkt[((long)j * 4 + b) * 1024 + col];
    S[b * 1024 + col] = s;
}

// ---------------- epilogue: y = [cos(pq),sin(pq)]/sqrt(8) @ S ----------------
// Compute per (row, d-block) as before, then LDS-shuffle so stores are
// 16 x 1KB lane-contiguous per wave (old path: 16B chunks @256B lane stride).
__global__ __launch_bounds__(256) void favor_out(
    const float* __restrict__ pq,   // [NROWS][8]
    const float* __restrict__ S,    // [4][16][64]
    float* __restrict__ y)          // [NROWS][64]
{
    __shared__ __align__(16) float Ly[64 * 68];   // 17408 B

    const int tid = threadIdx.x;
    const int blk = blockIdx.x;     // 0..511
    const int lane = tid & 63;
    const int w = __builtin_amdgcn_readfirstlane(tid >> 6);  // d-block 0..3
    const long row = (long)blk * 64 + lane;
    const int b = blk >> 7;         // 128 blocks per batch

    const float4 p0 = *(const float4*)(pq + row * 8);
    const float4 p1 = *(const float4*)(pq + row * 8 + 4);
    float qp[16];
    qp[0] = __cosf(p0.x) * INV_SQRT8;  qp[1] = __cosf(p0.y) * INV_SQRT8;
    qp[2] = __cosf(p0.z) * INV_SQRT8;  qp[3] = __cosf(p0.w) * INV_SQRT8;
    qp[4] = __cosf(p1.x) * INV_SQRT8;  qp[5] = __cosf(p1.y) * INV_SQRT8;
    qp[6] = __cosf(p1.z) * INV_SQRT8;  qp[7] = __cosf(p1.w) * INV_SQRT8;
    qp[8] = __sinf(p0.x) * INV_SQRT8;  qp[9] = __sinf(p0.y) * INV_SQRT8;
    qp[10]= __sinf(p0.z) * INV_SQRT8;  qp[11]= __sinf(p0.w) * INV_SQRT8;
    qp[12]= __sinf(p1.x) * INV_SQRT8;  qp[13]= __sinf(p1.y) * INV_SQRT8;
    qp[14]= __sinf(p1.z) * INV_SQRT8;  qp[15]= __sinf(p1.w) * INV_SQRT8;

    const float* Sb = S + b * 1024 + w * 16;   // wave-uniform -> scalar loads
    float a[16];
    #pragma unroll
    for (int i = 0; i < 16; ++i) a[i] = 0.f;
    #pragma unroll
    for (int m = 0; m < 16; ++m) {
        const float4 s0 = *(const float4*)(Sb + m * 64);
        const float4 s1 = *(const float4*)(Sb + m * 64 + 4);
        const float4 s2 = *(const float4*)(Sb + m * 64 + 8);
        const float4 s3 = *(const float4*)(Sb + m * 64 + 12);
        const float qm = qp[m];
        a[0] += qm * s0.x;  a[1] += qm * s0.y;  a[2] += qm * s0.z;  a[3] += qm * s0.w;
        a[4] += qm * s1.x;  a[5] += qm * s1.y;  a[6] += qm * s1.z;  a[7] += qm * s1.w;
        a[8] += qm * s2.x;  a[9] += qm * s2.y;  a[10]+= qm * s2.z;  a[11]+= qm * s2.w;
        a[12]+= qm * s3.x;  a[13]+= qm * s3.y;  a[14]+= qm * s3.z;  a[15]+= qm * s3.w;
    }
    // stage into LDS: Ly[local row][w*16 + j]
    {
        float* lw = Ly + lane * 68 + w * 16;
        *(float4*)(lw)      = make_float4(a[0],  a[1],  a[2],  a[3]);
        *(float4*)(lw + 4)  = make_float4(a[4],  a[5],  a[6],  a[7]);
        *(float4*)(lw + 8)  = make_float4(a[8],  a[9],  a[10], a[11]);
        *(float4*)(lw + 12) = make_float4(a[12], a[13], a[14], a[15]);
    }
    __syncthreads();
    // contiguous store: wave w writes local rows [w*16, w*16+16) = 4KB in 4x1KB instrs
    {
        const float* ls = Ly + (w * 16 + (lane >> 4)) * 68 + (lane & 15) * 4;
        float* yb = y + (long)blk * 4096 + w * 1024 + lane * 4;
        #pragma unroll
        for (int i = 0; i < 4; ++i) {
            const float4 v = *(const float4*)(ls + i * 4 * 68);
            *(float4*)(yb + i * 256) = v;
        }
    }
}

extern "C" void kernel_launch(void* const* d_in, const int* in_sizes, int n_in,
                              void* d_out, int out_size, void* d_ws, size_t ws_size,
                              hipStream_t stream) {
    const float* x  = (const float*)d_in[0];
    const float* w  = (const float*)d_in[1];
    const float* Wq = (const float*)d_in[2];
    const float* bq = (const float*)d_in[3];
    const float* Wk = (const float*)d_in[4];
    const float* bk = (const float*)d_in[5];
    const float* Wv = (const float*)d_in[6];
    const float* bv = (const float*)d_in[7];
    float* y = (float*)d_out;

    char* ws = (char*)d_ws;
    float*  S    = (float*)(ws);             // 16 KB   [4][1024]
    float*  bqw  = (float*)(ws + 16384);
    float*  bkw  = (float*)(ws + 16448);
    __bf16* WpHS = (__bf16*)(ws + 32768);    // 32 KB   [32][64][8]
    __bf16* WpLS = (__bf16*)(ws + 65536);    // 32 KB
    __bf16* WvS  = (__bf16*)(ws + 98304);    // 128 KB  [4][32][64][8]
    float*  Sbkt = (float*)(ws + 229376);    // 2 MB    [128][4][1024]
    float*  pq   = (float*)(ws + 2326528);   // 1 MB    [32768][8]

    hipMemsetAsync(Sbkt, 0, 128 * 4 * 1024 * sizeof(float), stream);
    favor_setup<<<64, 256, 0, stream>>>(w, Wq, bq, Wk, bk, Wv, bqw, bkw, WpHS, WpLS, WvS);
    favor_main<<<2048, 256, 0, stream>>>(x, WvS, WpHS, WpLS, bqw, bkw, bv, pq, Sbkt);
    favor_reduce<<<16, 256, 0, stream>>>(Sbkt, S);
    favor_out<<<512, 256, 0, stream>>>(pq, S, y);
}

// Round 6
// 227.125 us; speedup vs baseline: 1.1472x; 1.1472x over previous
//
#include <hip/hip_runtime.h>
#include <cstdint>

#define E_DIM 1024
#define NROWS 32768
#define LDT 260                 // padded LDS row stride (floats) per stage buffer
#define INV_SQRT8 0.35355339059327373f

typedef __bf16 bf16x8 __attribute__((ext_vector_type(8)));
typedef float f32x4 __attribute__((ext_vector_type(4)));
typedef const __attribute__((address_space(1))) void* gas_t;
typedef __attribute__((address_space(3))) void* las_t;

// ---------------- setup: fold W'=W@w, emit MFMA-fragment-swizzled bf16 tables ----------------
// WpHS/WpLS: [32 step][64 lane][8 j]  (hi/lo split of [Wq@w | Wk@w], B-frag order)
// WvS:       [4 ct][32 step][64 lane][8 j] of Wv (B-frag order)
__global__ __launch_bounds__(256) void favor_setup(
    const float* __restrict__ w,     // [64][8]
    const float* __restrict__ Wq,    // [1024][64]
    const float* __restrict__ bq,    // [64]
    const float* __restrict__ Wk,    // [1024][64]
    const float* __restrict__ bk,    // [64]
    const float* __restrict__ Wv,    // [1024][64]
    float* __restrict__ bqw,         // [8]
    float* __restrict__ bkw,         // [8]
    __bf16* __restrict__ WpHS,
    __bf16* __restrict__ WpLS,
    __bf16* __restrict__ WvS)
{
    const int g = blockIdx.x * 256 + threadIdx.x;  // 0..16383
    {
        const int k = g >> 4;
        const int c = g & 15;
        const float* Wsrc = (c < 8) ? Wq : Wk;
        const int cc = c & 7;
        float s = 0.f;
        #pragma unroll 8
        for (int d = 0; d < 64; ++d)
            s += Wsrc[k * 64 + d] * w[d * 8 + cc];
        const __bf16 h = (__bf16)s;
        const int step = k >> 5, quad = (k >> 3) & 3, j = k & 7;
        const int lane = quad * 16 + c;
        const int idx = (step * 64 + lane) * 8 + j;
        WpHS[idx] = h;
        WpLS[idx] = (__bf16)(s - (float)h);
    }
    #pragma unroll
    for (int t = 0; t < 4; ++t) {
        const int idx = g * 4 + t;        // [0, 65536)
        const int n = idx >> 10;          // 0..63
        const int k = idx & 1023;
        const int ct = n >> 4, l15 = n & 15;
        const int step = k >> 5, quad = (k >> 3) & 3, j = k & 7;
        const int lane = quad * 16 + l15;
        WvS[(((ct * 32 + step) * 64) + lane) * 8 + j] = (__bf16)Wv[k * 64 + n];
    }
    if (g < 16) {
        const int col = g & 7;
        const float* bb = (g < 8) ? bq : bk;
        float s1 = 0.f;
        #pragma unroll 8
        for (int d = 0; d < 64; ++d)
            s1 += bb[d] * w[d * 8 + col];
        if (g < 8) bqw[col] = s1; else bkw[col] = s1;
    }
}

// ---------------- main ----------------
// grid 2048 x 256. Block = 16 rows. K staged in 4 stages of 256 cols,
// double-buffered (2 x 16x260 floats = 33.3KB -> 4 blocks/CU).
// Staging: global_load_lds width=16, one instr per row (1KB lane-contiguous,
// no permute), dest base wave-uniform (padding legal per-instr).
// Compute: wave wv covers local cols [wv*64, wv*64+64) of each stage.
// S-partials: plain per-block store (NO atomics), reduced by favor_reduce.
__global__ __launch_bounds__(256, 4) void favor_main(
    const float* __restrict__ x,      // [NROWS][1024]
    const __bf16* __restrict__ WvS,   // [4][32][64][8]
    const __bf16* __restrict__ WpHS,  // [32][64][8]
    const __bf16* __restrict__ WpLS,  // [32][64][8]
    const float* __restrict__ bqw,    // [8]
    const float* __restrict__ bkw,    // [8]
    const float* __restrict__ bv,     // [64]
    float* __restrict__ pq_out,       // [NROWS][8]
    float* __restrict__ Sbkt)         // [2048][1024]
{
    __shared__ __align__(16) float smem[2 * 16 * LDT];   // 33280 floats? no: 8320 floats = 33280 B
    float* buf0 = smem;                // [16][260]
    float* buf1 = smem + 16 * LDT;
    // tail overlays (phases separated by barriers; writers don't alias live readers):
    float* bufW = smem;                // [3][64][20] = 3840 f  (combine payload)
    float* vb   = smem + 3840;         // [16][68]    = 1088 f
    float* kp   = smem + 4928;         // [16][16]    = 256 f
    float* sred = smem + 5248;         // [3][64][20] = 3840 f  -> ends 9088 > 8320? NO -> place sred at 0 (bufW dead)

    const int tid  = threadIdx.x;
    const int wg   = blockIdx.x;                                // 0..2047
    const int lane = tid & 63;
    const int wv   = __builtin_amdgcn_readfirstlane(tid >> 6);  // 0..3
    const int l15  = lane & 15;
    const int quad = lane >> 4;

    // staging source base: wave wv loads rows wv*4..wv*4+3
    const float* xs = x + ((long)wg * 16 + wv * 4) * E_DIM + lane * 4;
    const int ldsrow = wv * 4;

#define PF(buf, s)                                                             \
    _Pragma("unroll")                                                          \
    for (int r = 0; r < 4; ++r)                                                \
        __builtin_amdgcn_global_load_lds(                                      \
            (gas_t)(xs + r * E_DIM + (s) * 256),                               \
            (las_t)((buf) + (ldsrow + r) * LDT), 16, 0, 0);

    f32x4 zero = {0.f, 0.f, 0.f, 0.f};
    f32x4 accv[4];
    #pragma unroll
    for (int ct = 0; ct < 4; ++ct) accv[ct] = zero;
    f32x4 accp = zero;

    PF(buf0, 0)
    __syncthreads();

    #pragma unroll
    for (int s = 0; s < 4; ++s) {
        float* wb = (s & 1) ? buf1 : buf0;
        if (s < 3) {
            float* nb = (s & 1) ? buf0 : buf1;
            PF(nb, s + 1)
        }
        #pragma unroll
        for (int ks = 0; ks < 2; ++ks) {
            const float* ap = wb + l15 * LDT + wv * 64 + ks * 32 + quad * 8;
            const float4 a0 = *(const float4*)ap;
            const float4 a1 = *(const float4*)(ap + 4);
            bf16x8 ah, al;
            {
                const float f[8] = {a0.x, a0.y, a0.z, a0.w, a1.x, a1.y, a1.z, a1.w};
                #pragma unroll
                for (int i = 0; i < 8; ++i) {
                    const __bf16 h = (__bf16)f[i];
                    ah[i] = h; al[i] = (__bf16)(f[i] - (float)h);
                }
            }
            const int gs = s * 8 + wv * 2 + ks;
            const __bf16* bp = WvS + (long)gs * 512 + lane * 8;
            #pragma unroll
            for (int ct = 0; ct < 4; ++ct) {
                const bf16x8 b = *(const bf16x8*)(bp + ct * 16384);
                accv[ct] = __builtin_amdgcn_mfma_f32_16x16x32_bf16(ah, b, accv[ct], 0, 0, 0);
            }
            {
                const bf16x8 bh = *(const bf16x8*)(WpHS + (long)gs * 512 + lane * 8);
                const bf16x8 bl = *(const bf16x8*)(WpLS + (long)gs * 512 + lane * 8);
                accp = __builtin_amdgcn_mfma_f32_16x16x32_bf16(ah, bh, accp, 0, 0, 0);
                accp = __builtin_amdgcn_mfma_f32_16x16x32_bf16(al, bh, accp, 0, 0, 0);
                accp = __builtin_amdgcn_mfma_f32_16x16x32_bf16(ah, bl, accp, 0, 0, 0);
            }
        }
        __syncthreads();
    }
#undef PF

    // ---- combine K-quarters: waves 1..3 dump, wave 0 sums ----
    if (wv != 0) {
        float* dst = bufW + ((wv - 1) * 64 + lane) * 20;
        #pragma unroll
        for (int ct = 0; ct < 4; ++ct)
            *(f32x4*)(dst + ct * 4) = accv[ct];
        *(f32x4*)(dst + 16) = accp;
    }
    __syncthreads();
    if (wv == 0) {
        #pragma unroll
        for (int j = 0; j < 3; ++j) {
            const float* src = bufW + (j * 64 + lane) * 20;
            #pragma unroll
            for (int ct = 0; ct < 4; ++ct)
                accv[ct] += *(const f32x4*)(src + ct * 4);
            accp += *(const f32x4*)(src + 16);
        }
        // ---- p epilogue: accp[r] = P[row = quad*4 + r][c = l15] ----
        if (l15 < 8) {
            const float bq_ = bqw[l15];
            #pragma unroll
            for (int r = 0; r < 4; ++r) {
                const long gr = (long)wg * 16 + quad * 4 + r;
                pq_out[gr * 8 + l15] = accp[r] + bq_;
            }
        } else {
            const float bk_ = bkw[l15 - 8];
            #pragma unroll
            for (int r = 0; r < 4; ++r) {
                const int lr = quad * 4 + r;
                const float pk_ = accp[r] + bk_;
                kp[lr * 16 + (l15 - 8)] = __cosf(pk_) * INV_SQRT8;
                kp[lr * 16 + l15]       = __sinf(pk_) * INV_SQRT8;
            }
        }
        // ---- v epilogue: C/D layout col=lane&15, row=quad*4+reg ----
        #pragma unroll
        for (int ct = 0; ct < 4; ++ct) {
            const float bv_ = bv[ct * 16 + l15];
            #pragma unroll
            for (int r = 0; r < 4; ++r)
                vb[(quad * 4 + r) * 68 + ct * 16 + l15] = accv[ct][r] + bv_;
        }
    }
    __syncthreads();   // bufW dead from here; sred overlays it (offset 0)

    // ---- S partial: S[m][d] = sum_r kp[r][m]*vb[r][d] over 16 rows; plain store ----
    {
        float* sredo = smem;         // [3][64][20], overlays dead bufW
        const int d4 = l15;          // d block of 4
        const int mg = quad;         // m block of 4
        const int rq = wv;           // row quarter (4 rows)
        float sa[16];
        #pragma unroll
        for (int i = 0; i < 16; ++i) sa[i] = 0.f;
        #pragma unroll
        for (int rr = 0; rr < 4; ++rr) {
            const int r = rq * 4 + rr;
            const float4 vv  = *(const float4*)(vb + r * 68 + d4 * 4);
            const float4 kk4 = *(const float4*)(kp + r * 16 + mg * 4);
            const float km[4] = {kk4.x, kk4.y, kk4.z, kk4.w};
            const float vm[4] = {vv.x, vv.y, vv.z, vv.w};
            #pragma unroll
            for (int mi = 0; mi < 4; ++mi)
                #pragma unroll
                for (int di = 0; di < 4; ++di)
                    sa[mi * 4 + di] += km[mi] * vm[di];
        }
        if (rq > 0) {
            float* dst = sredo + ((rq - 1) * 64 + lane) * 20;
            #pragma unroll
            for (int i = 0; i < 4; ++i)
                *(float4*)(dst + i * 4) = make_float4(sa[i*4], sa[i*4+1], sa[i*4+2], sa[i*4+3]);
        }
        __syncthreads();
        if (rq == 0) {
            #pragma unroll
            for (int j = 0; j < 3; ++j) {
                const float* src = sredo + (j * 64 + lane) * 20;
                #pragma unroll
                for (int i = 0; i < 16; ++i) sa[i] += src[i];
            }
            float* Sb = Sbkt + (long)wg * 1024;
            #pragma unroll
            for (int mi = 0; mi < 4; ++mi)
                *(float4*)(Sb + (mg * 4 + mi) * 64 + d4 * 4) =
                    make_float4(sa[mi*4], sa[mi*4+1], sa[mi*4+2], sa[mi*4+3]);
        }
    }
}

// ---------------- reduce per-block partials -> S ----------------
// grid 64 x 256: block = (batch b, 64-col chunk cc). Thread = (col c, j-quarter jq);
// sums 128 of the batch's 512 block-partials, LDS tree 4->1.
__global__ __launch_bounds__(256) void favor_reduce(
    const float* __restrict__ Sbkt,   // [2048][1024]
    float* __restrict__ S)            // [4][1024]
{
    __shared__ float red[3][64];
    const int b  = blockIdx.x >> 4;          // 0..3
    const int cc = blockIdx.x & 15;          // 0..15
    const int c  = threadIdx.x & 63;
    const int jq = threadIdx.x >> 6;
    const int col = cc * 64 + c;
    const float* base = Sbkt + ((long)b * 512 + jq * 128) * 1024 + col;
    float s = 0.f;
    #pragma unroll 16
    for (int j = 0; j < 128; ++j)
        s += base[(long)j * 1024];
    if (jq > 0) red[jq - 1][c] = s;
    __syncthreads();
    if (jq == 0)
        S[b * 1024 + col] = s + red[0][c] + red[1][c] + red[2][c];
}

// ---------------- epilogue: y = [cos(pq),sin(pq)]/sqrt(8) @ S ----------------
__global__ __launch_bounds__(256) void favor_out(
    const float* __restrict__ pq,   // [NROWS][8]
    const float* __restrict__ S,    // [4][16][64]
    float* __restrict__ y)          // [NROWS][64]
{
    __shared__ __align__(16) float Ly[64 * 68];   // 17408 B

    const int tid = threadIdx.x;
    const int blk = blockIdx.x;     // 0..511
    const int lane = tid & 63;
    const int w = __builtin_amdgcn_readfirstlane(tid >> 6);  // d-block 0..3
    const long row = (long)blk * 64 + lane;
    const int b = blk >> 7;         // 128 blocks per batch

    const float4 p0 = *(const float4*)(pq + row * 8);
    const float4 p1 = *(const float4*)(pq + row * 8 + 4);
    float qp[16];
    qp[0] = __cosf(p0.x) * INV_SQRT8;  qp[1] = __cosf(p0.y) * INV_SQRT8;
    qp[2] = __cosf(p0.z) * INV_SQRT8;  qp[3] = __cosf(p0.w) * INV_SQRT8;
    qp[4] = __cosf(p1.x) * INV_SQRT8;  qp[5] = __cosf(p1.y) * INV_SQRT8;
    qp[6] = __cosf(p1.z) * INV_SQRT8;  qp[7] = __cosf(p1.w) * INV_SQRT8;
    qp[8] = __sinf(p0.x) * INV_SQRT8;  qp[9] = __sinf(p0.y) * INV_SQRT8;
    qp[10]= __sinf(p0.z) * INV_SQRT8;  qp[11]= __sinf(p0.w) * INV_SQRT8;
    qp[12]= __sinf(p1.x) * INV_SQRT8;  qp[13]= __sinf(p1.y) * INV_SQRT8;
    qp[14]= __sinf(p1.z) * INV_SQRT8;  qp[15]= __sinf(p1.w) * INV_SQRT8;

    const float* Sb = S + b * 1024 + w * 16;   // wave-uniform -> scalar loads
    float a[16];
    #pragma unroll
    for (int i = 0; i < 16; ++i) a[i] = 0.f;
    #pragma unroll
    for (int m = 0; m < 16; ++m) {
        const float4 s0 = *(const float4*)(Sb + m * 64);
        const float4 s1 = *(const float4*)(Sb + m * 64 + 4);
        const float4 s2 = *(const float4*)(Sb + m * 64 + 8);
        const float4 s3 = *(const float4*)(Sb + m * 64 + 12);
        const float qm = qp[m];
        a[0] += qm * s0.x;  a[1] += qm * s0.y;  a[2] += qm * s0.z;  a[3] += qm * s0.w;
        a[4] += qm * s1.x;  a[5] += qm * s1.y;  a[6] += qm * s1.z;  a[7] += qm * s1.w;
        a[8] += qm * s2.x;  a[9] += qm * s2.y;  a[10]+= qm * s2.z;  a[11]+= qm * s2.w;
        a[12]+= qm * s3.x;  a[13]+= qm * s3.y;  a[14]+= qm * s3.z;  a[15]+= qm * s3.w;
    }
    {
        float* lw = Ly + lane * 68 + w * 16;
        *(float4*)(lw)      = make_float4(a[0],  a[1],  a[2],  a[3]);
        *(float4*)(lw + 4)  = make_float4(a[4],  a[5],  a[6],  a[7]);
        *(float4*)(lw + 8)  = make_float4(a[8],  a[9],  a[10], a[11]);
        *(float4*)(lw + 12) = make_float4(a[12], a[13], a[14], a[15]);
    }
    __syncthreads();
    {
        const float* ls = Ly + (w * 16 + (lane >> 4)) * 68 + (lane & 15) * 4;
        float* yb = y + (long)blk * 4096 + w * 1024 + lane * 4;
        #pragma unroll
        for (int i = 0; i < 4; ++i) {
            const float4 v = *(const float4*)(ls + i * 4 * 68);
            *(float4*)(yb + i * 256) = v;
        }
    }
}

extern "C" void kernel_launch(void* const* d_in, const int* in_sizes, int n_in,
                              void* d_out, int out_size, void* d_ws, size_t ws_size,
                              hipStream_t stream) {
    const float* x  = (const float*)d_in[0];
    const float* w  = (const float*)d_in[1];
    const float* Wq = (const float*)d_in[2];
    const float* bq = (const float*)d_in[3];
    const float* Wk = (const float*)d_in[4];
    const float* bk = (const float*)d_in[5];
    const float* Wv = (const float*)d_in[6];
    const float* bv = (const float*)d_in[7];
    float* y = (float*)d_out;

    char* ws = (char*)d_ws;
    float*  S    = (float*)(ws);             // 16 KB   [4][1024]
    float*  bqw  = (float*)(ws + 16384);
    float*  bkw  = (float*)(ws + 16448);
    __bf16* WpHS = (__bf16*)(ws + 32768);    // 32 KB   [32][64][8]
    __bf16* WpLS = (__bf16*)(ws + 65536);    // 32 KB
    __bf16* WvS  = (__bf16*)(ws + 98304);    // 128 KB  [4][32][64][8]
    float*  Sbkt = (float*)(ws + 229376);    // 8 MB    [2048][1024]
    float*  pq   = (float*)(ws + 8617984);   // 1 MB    [32768][8]

    favor_setup<<<64, 256, 0, stream>>>(w, Wq, bq, Wk, bk, Wv, bqw, bkw, WpHS, WpLS, WvS);
    favor_main<<<2048, 256, 0, stream>>>(x, WvS, WpHS, WpLS, bqw, bkw, bv, pq, Sbkt);
    favor_reduce<<<64, 256, 0, stream>>>(Sbkt, S);
    favor_out<<<512, 256, 0, stream>>>(pq, S, y);
}